// Round 3
// baseline (565.738 us; speedup 1.0000x reference)
//
#include <hip/hip_runtime.h>
#include <hip/hip_bf16.h>

#define N_NODES 10000
#define IN_DIM 512
#define HID 128
#define NPAD 10240   // 256*40: row pad for wide MFMA tiles + scan coverage

typedef __attribute__((ext_vector_type(8))) __bf16 bf16x8;
typedef __attribute__((ext_vector_type(8))) unsigned short u16x8;
typedef __attribute__((ext_vector_type(4))) float f32x4;

// RNE float->bf16 (values are well-behaved normals; no NaN path needed)
__device__ __forceinline__ unsigned short f2bf(float f) {
    unsigned int u = __float_as_uint(f);
    return (unsigned short)((u + 0x7fffu + ((u >> 16) & 1u)) >> 16);
}

// async global->LDS, 16B per lane; dest = uniform base + lane*16, src per-lane
__device__ __forceinline__ void gload_lds16(const void* g, void* l) {
    __builtin_amdgcn_global_load_lds(
        (const __attribute__((address_space(1))) unsigned int*)g,
        (__attribute__((address_space(3))) unsigned int*)l, 16, 0, 0);
}

// ---------- CSR build ----------
__global__ void k_zero_cnt(int* cnt) {
    int i = blockIdx.x * 256 + threadIdx.x;
    if (i < NPAD) cnt[i] = 0;
}

__global__ void k_hist(const int* __restrict__ ei, int* cnt, int E) {
    int e = blockIdx.x * 256 + threadIdx.x;
    if (e < E) atomicAdd(&cnt[ei[E + e]], 1);
}

// single block, 256 threads: exclusive scan of cnt[0..NPAD) -> base & cursor,
// plus dinv[i] = rsqrt(in_deg + 1) for the symmetric GCN norm.
__global__ void k_scan(const int* __restrict__ cnt, int* __restrict__ base,
                       int* __restrict__ cursor, float* __restrict__ dinv) {
    __shared__ int lds[256];
    int t = threadIdx.x;
    int loc[40];
    int sum = 0;
#pragma unroll
    for (int j = 0; j < 40; ++j) {
        int idx = t * 40 + j;
        int c = cnt[idx];
        loc[j] = sum;       // exclusive local prefix
        sum += c;
    }
    lds[t] = sum;
    __syncthreads();
    for (int off = 1; off < 256; off <<= 1) {
        int v = (t >= off) ? lds[t - off] : 0;
        __syncthreads();
        lds[t] += v;
        __syncthreads();
    }
    int ex = lds[t] - sum;  // exclusive block prefix for this thread
#pragma unroll
    for (int j = 0; j < 40; ++j) {
        int idx = t * 40 + j;
        int b = ex + loc[j];
        base[idx] = b;
        cursor[idx] = b;
        dinv[idx] = rsqrtf((float)cnt[idx] + 1.0f);
    }
}

__global__ void k_fill(const int* __restrict__ ei, const float* __restrict__ dinv,
                       int* cursor, int2* __restrict__ csr, int E) {
    int e = blockIdx.x * 256 + threadIdx.x;
    if (e >= E) return;
    int s = ei[e];
    int d = ei[E + e];
    int pos = atomicAdd(&cursor[d], 1);
    float w = dinv[s] * dinv[d];
    csr[pos] = make_int2(s, __float_as_int(w));
}

// ---------- W_enc cast (tiny: 128x512) ----------
__global__ void k_cast_wenc(const float* __restrict__ w, __hip_bfloat16* __restrict__ wT) {
    int idx = blockIdx.x * 256 + threadIdx.x;   // over HID*IN_DIM
    int n = idx & (HID - 1);
    int k = idx >> 7;
    wT[n * IN_DIM + k] = __float2bfloat16(w[k * HID + n]);
}

// ---------- W_dec transpose+cast via LDS (coalesced reads AND writes) ----------
// grid (NPAD/32=320, HID/32=4), block (32,8)
__global__ __launch_bounds__(256) void k_wdec_t(const float* __restrict__ wdec,
                                                __hip_bfloat16* __restrict__ wT) {
    __shared__ float tile[32][33];
    int tx = threadIdx.x, ty = threadIdx.y;
    int n0 = blockIdx.x * 32, k0 = blockIdx.y * 32;
#pragma unroll
    for (int j = 0; j < 4; ++j) {
        int k = k0 + ty * 4 + j;
        int n = n0 + tx;
        tile[ty * 4 + j][tx] = (n < N_NODES) ? wdec[(size_t)k * N_NODES + n] : 0.0f;
    }
    __syncthreads();
#pragma unroll
    for (int j = 0; j < 4; ++j) {
        int n = n0 + ty * 4 + j;
        int k = k0 + tx;
        wT[(size_t)n * HID + k] = __float2bfloat16(tile[tx][ty * 4 + j]);
    }
}

// ---------- encoder GEMM, fused f32->bf16 on the fly: h = x @ W_enc ----------
// tile 32(m) x 128(n), 4 waves as 2x2, each wave 16x64. grid = ceil(10000/32)=313
__global__ __launch_bounds__(256) void k_enc_gemm(
    const float* __restrict__ x, const __hip_bfloat16* __restrict__ wencT,
    float* __restrict__ h)
{
    int tid = threadIdx.x;
    int wv = tid >> 6, lane = tid & 63;
    int l16 = lane & 15, quad = lane >> 4;
    int m_w = blockIdx.x * 32 + (wv >> 1) * 16;
    int n_w = (wv & 1) * 64;
    f32x4 acc[4] = {};
    int row = m_w + l16;
    bool rv = row < N_NODES;
    const float* xr = x + (size_t)row * IN_DIM;
    for (int kk = 0; kk < IN_DIM; kk += 32) {
        int k0 = kk + quad * 8;
        f32x4 u = {}, w = {};
        if (rv) {
            u = *(const f32x4*)(xr + k0);
            w = *(const f32x4*)(xr + k0 + 4);
        }
        union { u16x8 u; bf16x8 v; } a;
#pragma unroll
        for (int j = 0; j < 4; ++j) {
            a.u[j] = f2bf(u[j]);
            a.u[4 + j] = f2bf(w[j]);
        }
        bf16x8 b[4];
#pragma unroll
        for (int ni = 0; ni < 4; ++ni)
            b[ni] = *(const bf16x8*)(const void*)(wencT + (size_t)(n_w + ni * 16 + l16) * IN_DIM + k0);
#pragma unroll
        for (int ni = 0; ni < 4; ++ni)
            acc[ni] = __builtin_amdgcn_mfma_f32_16x16x32_bf16(a.v, b[ni], acc[ni], 0, 0, 0);
    }
    // C/D: col = l16 (n), row = quad*4+r (m)
#pragma unroll
    for (int ni = 0; ni < 4; ++ni) {
        int n = n_w + ni * 16 + l16;
#pragma unroll
        for (int r = 0; r < 4; ++r) {
            int m = m_w + quad * 4 + r;
            if (m < N_NODES) h[(size_t)m * HID + n] = acc[ni][r];
        }
    }
}

// ---------- fused aggregate + bias + bf16 cast (4-way ILP, 2 rows/block) ----------
__global__ __launch_bounds__(256) void k_agg_enc(
    const float* __restrict__ h, const int2* __restrict__ csr,
    const int* __restrict__ base, const int* __restrict__ cnt,
    const float* __restrict__ dinv, const float* __restrict__ b_enc,
    __hip_bfloat16* __restrict__ enc)
{
    int i = blockIdx.x * 2 + (threadIdx.x >> 7);
    int t = threadIdx.x & 127;
    if (i >= N_NODES) {                      // pad rows for the MFMA decoder
        enc[(size_t)i * HID + t] = __float2bfloat16(0.0f);
        return;
    }
    float di = dinv[i];
    float a0 = di * di * h[(size_t)i * HID + t];
    float a1 = 0.0f, a2 = 0.0f, a3 = 0.0f;
    int j0 = base[i], d = cnt[i];
    int q4 = d >> 2;
    const int2* c0 = csr + j0;
    const int2* c1 = c0 + q4;
    const int2* c2 = c1 + q4;
    const int2* c3 = c2 + q4;
    for (int off = 0; off < q4; ++off) {
        int2 p0 = c0[off], p1 = c1[off], p2 = c2[off], p3 = c3[off];
        a0 += __int_as_float(p0.y) * h[(size_t)p0.x * HID + t];
        a1 += __int_as_float(p1.y) * h[(size_t)p1.x * HID + t];
        a2 += __int_as_float(p2.y) * h[(size_t)p2.x * HID + t];
        a3 += __int_as_float(p3.y) * h[(size_t)p3.x * HID + t];
    }
    for (int j = j0 + (q4 << 2); j < j0 + d; ++j) {
        int2 p = csr[j];
        a0 += __int_as_float(p.y) * h[(size_t)p.x * HID + t];
    }
    enc[(size_t)i * HID + t] = __float2bfloat16(((a0 + a1) + (a2 + a3)) + b_enc[t]);
}

// ---------- decoder GEMM + bias + sigmoid, LDS-staged 128x128 tile ----------
// 64 KiB LDS -> 2 blocks/CU: one block's store drain overlaps the other's
// stage+compute, keeping the write pipe (the 400 MB / 67 us floor) busy.
// K = HID = 128 staged in one shot. 4 waves as 2(m)x2(n), wave tile 64x64.
// LDS XOR swizzle (byte ^= (row&7)<<4) on BOTH global source (linear LDS dest)
// and ds_read addresses. Operand-swapped MFMA (acc = mfma(b, a, acc)):
//   value = C[m = mbase+mi*16+l16][n = nbase+ni*16+quad*4+r] -> aligned f32x4 stores.
__global__ __launch_bounds__(256) void k_dec_gemm(
    const __hip_bfloat16* __restrict__ A, const __hip_bfloat16* __restrict__ BT,
    const float* __restrict__ bias, float* __restrict__ C)
{
    extern __shared__ char lds[];
    char* ldsA = lds;             // 32768 B (128 rows x 256 B)
    char* ldsB = lds + 32768;     // 32768 B

    const int NT = 80;            // 80x80 = 6400 blocks, %8==0 -> bijective swizzle
    int orig = blockIdx.x;
    int wg = (orig & 7) * 800 + (orig >> 3);
    int bx = wg % NT, by = wg / NT;   // consecutive wg in an XCD share by -> A panel L2-hot

    int tid = threadIdx.x;
    int wv = tid >> 6, lane = tid & 63;
    int l16 = lane & 15, quad = lane >> 4;
    int wm = wv >> 1, wn = wv & 1;

    // ---- stage both tiles (each wave: 8 x 1KB for A, 8 x 1KB for B) ----
    {
        const char* gA = (const char*)A + (size_t)by * 32768;
        const char* gB = (const char*)BT + (size_t)bx * 32768;
        int wb = wv * 1024;
#pragma unroll
        for (int it = 0; it < 8; ++it) {
            int L = wb + it * 4096 + lane * 16;     // linear LDS byte this lane fills
            int row = L >> 8;
            int src = (row << 8) | ((L & 255) ^ ((row & 7) << 4));  // inverse-swizzled source
            gload_lds16(gA + src, ldsA + wb + it * 4096);
        }
#pragma unroll
        for (int it = 0; it < 8; ++it) {
            int L = wb + it * 4096 + lane * 16;
            int row = L >> 8;
            int src = (row << 8) | ((L & 255) ^ ((row & 7) << 4));
            gload_lds16(gB + src, ldsB + wb + it * 4096);
        }
    }
    asm volatile("s_waitcnt vmcnt(0)" ::: "memory");
    __syncthreads();

    // ---- compute: 4 K-steps x (4 b-frags + 4 a-frags) x 16 MFMA ----
    f32x4 acc[4][4] = {};
    int qb = quad * 16;
#pragma unroll
    for (int ks = 0; ks < 4; ++ks) {
        int kb = ks * 64 + qb;      // byte col of this lane's 16B fragment (pre-swizzle)
        bf16x8 a[4], b[4];
#pragma unroll
        for (int ni = 0; ni < 4; ++ni) {
            int r = wn * 64 + ni * 16 + l16;
            b[ni] = *(const bf16x8*)(ldsB + ((r << 8) + (kb ^ ((r & 7) << 4))));
        }
#pragma unroll
        for (int mi = 0; mi < 4; ++mi) {
            int r = wm * 64 + mi * 16 + l16;
            a[mi] = *(const bf16x8*)(ldsA + ((r << 8) + (kb ^ ((r & 7) << 4))));
        }
#pragma unroll
        for (int mi = 0; mi < 4; ++mi)
#pragma unroll
            for (int ni = 0; ni < 4; ++ni)
                acc[mi][ni] = __builtin_amdgcn_mfma_f32_16x16x32_bf16(b[ni], a[mi], acc[mi][ni], 0, 0, 0);
    }

    // ---- epilogue: bias (hoisted) + sigmoid + aligned f32x4 stores ----
    int m_w = by * 128 + wm * 64;
    int n_w = bx * 128 + wn * 64;
    f32x4 bv[4];
#pragma unroll
    for (int ni = 0; ni < 4; ++ni) {
        int n4 = n_w + ni * 16 + quad * 4;
        bv[ni] = (n4 < N_NODES) ? *(const f32x4*)(bias + n4) : f32x4{};
    }
#pragma unroll
    for (int mi = 0; mi < 4; ++mi) {
        int m = m_w + mi * 16 + l16;
        if (m >= N_NODES) continue;
        size_t rowoff = (size_t)m * N_NODES;
#pragma unroll
        for (int ni = 0; ni < 4; ++ni) {
            int n4 = n_w + ni * 16 + quad * 4;
            if (n4 >= N_NODES) continue;
            f32x4 z = acc[mi][ni];
            f32x4 s;
#pragma unroll
            for (int r = 0; r < 4; ++r) {
                float e = __expf(-(z[r] + bv[ni][r]));
                s[r] = __builtin_amdgcn_rcpf(1.0f + e);
            }
            *(f32x4*)(C + rowoff + n4) = s;
        }
    }
}

extern "C" void kernel_launch(void* const* d_in, const int* in_sizes, int n_in,
                              void* d_out, int out_size, void* d_ws, size_t ws_size,
                              hipStream_t stream) {
    const float* x     = (const float*)d_in[0];
    const int*   ei    = (const int*)d_in[1];
    const float* W_enc = (const float*)d_in[2];
    const float* b_enc = (const float*)d_in[3];
    const float* W_dec = (const float*)d_in[4];
    const float* b_dec = (const float*)d_in[5];
    float* out = (float*)d_out;
    const int E = in_sizes[1] / 2;

    // carve workspace
    char* p = (char*)d_ws;
    auto carve = [&](size_t bytes) -> char* {
        char* r = p;
        p += (bytes + 255) & ~(size_t)255;
        return r;
    };
    int*   cnt    = (int*)carve((size_t)NPAD * 4);
    int*   base   = (int*)carve((size_t)NPAD * 4);
    int*   cursor = (int*)carve((size_t)NPAD * 4);
    float* dinv   = (float*)carve((size_t)NPAD * 4);
    int2*  csr    = (int2*)carve((size_t)E * 8);
    float* h      = (float*)carve((size_t)N_NODES * HID * 4);
    __hip_bfloat16* wencT = (__hip_bfloat16*)carve((size_t)HID * IN_DIM * 2);
    __hip_bfloat16* encb  = (__hip_bfloat16*)carve((size_t)NPAD * HID * 2);
    __hip_bfloat16* wdecT = (__hip_bfloat16*)carve((size_t)NPAD * HID * 2);

    // CSR build (counting sort by dst) + dinv
    k_zero_cnt<<<dim3(NPAD / 256), dim3(256), 0, stream>>>(cnt);
    k_hist<<<dim3((E + 255) / 256), dim3(256), 0, stream>>>(ei, cnt, E);
    k_scan<<<dim3(1), dim3(256), 0, stream>>>(cnt, base, cursor, dinv);
    k_fill<<<dim3((E + 255) / 256), dim3(256), 0, stream>>>(ei, dinv, cursor, csr, E);

    // weight preprocessing (independent of CSR chain)
    k_cast_wenc<<<dim3(HID * IN_DIM / 256), dim3(256), 0, stream>>>(W_enc, wencT);
    k_wdec_t<<<dim3(NPAD / 32, HID / 32), dim3(32, 8), 0, stream>>>(W_dec, wdecT);

    // encoder GEMM in bf16 (fused f32->bf16 load of x)
    k_enc_gemm<<<dim3((N_NODES + 31) / 32), dim3(256), 0, stream>>>(x, wencT, h);

    // fused aggregate + bias + bf16 cast (gather over CSR, no atomics)
    k_agg_enc<<<dim3(NPAD / 2), dim3(256), 0, stream>>>(h, csr, base, cnt, dinv, b_enc, encb);

    // decoder GEMM + bias + sigmoid: LDS-staged 128x128 tiles, 64 KiB LDS, 2 blocks/CU
    k_dec_gemm<<<dim3(80 * 80), dim3(256), 65536, stream>>>(encb, wdecT, b_dec, out);
}

// Round 4
// 548.024 us; speedup vs baseline: 1.0323x; 1.0323x over previous
//
#include <hip/hip_runtime.h>
#include <hip/hip_bf16.h>

#define N_NODES 10000
#define IN_DIM 512
#define HID 128
#define NPAD 10240   // 256*40: row pad for wide MFMA tiles + scan coverage

typedef __attribute__((ext_vector_type(8))) __bf16 bf16x8;
typedef __attribute__((ext_vector_type(8))) unsigned short u16x8;
typedef __attribute__((ext_vector_type(4))) float f32x4;

// RNE float->bf16 (values are well-behaved normals; no NaN path needed)
__device__ __forceinline__ unsigned short f2bf(float f) {
    unsigned int u = __float_as_uint(f);
    return (unsigned short)((u + 0x7fffu + ((u >> 16) & 1u)) >> 16);
}

// async global->LDS, 16B per lane; dest = uniform base + lane*16, src per-lane
__device__ __forceinline__ void gload_lds16(const void* g, void* l) {
    __builtin_amdgcn_global_load_lds(
        (const __attribute__((address_space(1))) unsigned int*)g,
        (__attribute__((address_space(3))) unsigned int*)l, 16, 0, 0);
}

// ---------- head-of-chain prep: zero cnt (blocks 0..39) + W_enc cast (rest) ----------
__global__ void k_prep(const float* __restrict__ w, __hip_bfloat16* __restrict__ wT,
                       int* __restrict__ cnt) {
    int b = blockIdx.x;
    if (b < 40) {
        cnt[b * 256 + threadIdx.x] = 0;
        return;
    }
    int idx = (b - 40) * 256 + threadIdx.x;   // over HID*IN_DIM
    int n = idx & (HID - 1);
    int k = idx >> 7;
    wT[n * IN_DIM + k] = __float2bfloat16(w[k * HID + n]);
}

__global__ void k_hist(const int* __restrict__ ei, int* cnt, int E) {
    int e = blockIdx.x * 256 + threadIdx.x;
    if (e < E) atomicAdd(&cnt[ei[E + e]], 1);
}

// single block, 1024 threads: exclusive scan of cnt[0..NPAD) -> base & cursor,
// plus dinv[i] = rsqrt(in_deg + 1) for the symmetric GCN norm.
__global__ __launch_bounds__(1024) void k_scan(
    const int* __restrict__ cnt, int* __restrict__ base,
    int* __restrict__ cursor, float* __restrict__ dinv) {
    __shared__ int lds[1024];
    int t = threadIdx.x;
    int loc[10];
    int sum = 0;
#pragma unroll
    for (int j = 0; j < 10; ++j) {
        int idx = t * 10 + j;
        int c = cnt[idx];
        loc[j] = sum;       // exclusive local prefix
        sum += c;
    }
    lds[t] = sum;
    __syncthreads();
    for (int off = 1; off < 1024; off <<= 1) {
        int v = (t >= off) ? lds[t - off] : 0;
        __syncthreads();
        lds[t] += v;
        __syncthreads();
    }
    int ex = lds[t] - sum;  // exclusive block prefix for this thread
#pragma unroll
    for (int j = 0; j < 10; ++j) {
        int idx = t * 10 + j;
        int b = ex + loc[j];
        base[idx] = b;
        cursor[idx] = b;
        dinv[idx] = rsqrtf((float)cnt[idx] + 1.0f);
    }
}

__global__ void k_fill(const int* __restrict__ ei, const float* __restrict__ dinv,
                       int* cursor, int2* __restrict__ csr, int E) {
    int e = blockIdx.x * 256 + threadIdx.x;
    if (e >= E) return;
    int s = ei[e];
    int d = ei[E + e];
    int pos = atomicAdd(&cursor[d], 1);
    float w = dinv[s] * dinv[d];
    csr[pos] = make_int2(s, __float_as_int(w));
}

// ---------- W_dec transpose+cast via LDS (coalesced reads AND writes) ----------
// grid (NPAD/32=320, HID/32=4), block (32,8)
__global__ __launch_bounds__(256) void k_wdec_t(const float* __restrict__ wdec,
                                                __hip_bfloat16* __restrict__ wT) {
    __shared__ float tile[32][33];
    int tx = threadIdx.x, ty = threadIdx.y;
    int n0 = blockIdx.x * 32, k0 = blockIdx.y * 32;
#pragma unroll
    for (int j = 0; j < 4; ++j) {
        int k = k0 + ty * 4 + j;
        int n = n0 + tx;
        tile[ty * 4 + j][tx] = (n < N_NODES) ? wdec[(size_t)k * N_NODES + n] : 0.0f;
    }
    __syncthreads();
#pragma unroll
    for (int j = 0; j < 4; ++j) {
        int n = n0 + ty * 4 + j;
        int k = k0 + tx;
        wT[(size_t)n * HID + k] = __float2bfloat16(tile[tx][ty * 4 + j]);
    }
}

// ---------- encoder GEMM, fused f32->bf16 on the fly: h = x @ W_enc ----------
// tile 32(m) x 128(n), 4 waves as 2x2, each wave 16x64. grid = ceil(10000/32)=313
__global__ __launch_bounds__(256) void k_enc_gemm(
    const float* __restrict__ x, const __hip_bfloat16* __restrict__ wencT,
    float* __restrict__ h)
{
    int tid = threadIdx.x;
    int wv = tid >> 6, lane = tid & 63;
    int l16 = lane & 15, quad = lane >> 4;
    int m_w = blockIdx.x * 32 + (wv >> 1) * 16;
    int n_w = (wv & 1) * 64;
    f32x4 acc[4] = {};
    int row = m_w + l16;
    bool rv = row < N_NODES;
    const float* xr = x + (size_t)row * IN_DIM;
    for (int kk = 0; kk < IN_DIM; kk += 32) {
        int k0 = kk + quad * 8;
        f32x4 u = {}, w = {};
        if (rv) {
            u = *(const f32x4*)(xr + k0);
            w = *(const f32x4*)(xr + k0 + 4);
        }
        union { u16x8 u; bf16x8 v; } a;
#pragma unroll
        for (int j = 0; j < 4; ++j) {
            a.u[j] = f2bf(u[j]);
            a.u[4 + j] = f2bf(w[j]);
        }
        bf16x8 b[4];
#pragma unroll
        for (int ni = 0; ni < 4; ++ni)
            b[ni] = *(const bf16x8*)(const void*)(wencT + (size_t)(n_w + ni * 16 + l16) * IN_DIM + k0);
#pragma unroll
        for (int ni = 0; ni < 4; ++ni)
            acc[ni] = __builtin_amdgcn_mfma_f32_16x16x32_bf16(a.v, b[ni], acc[ni], 0, 0, 0);
    }
    // C/D: col = l16 (n), row = quad*4+r (m)
#pragma unroll
    for (int ni = 0; ni < 4; ++ni) {
        int n = n_w + ni * 16 + l16;
#pragma unroll
        for (int r = 0; r < 4; ++r) {
            int m = m_w + quad * 4 + r;
            if (m < N_NODES) h[(size_t)m * HID + n] = acc[ni][r];
        }
    }
}

// ---------- fused aggregate + bias + bf16 cast ----------
// 2 rows per 256-thr block (no barriers; the two 128-thr halves are independent).
// Each wave does ONE coalesced int2 load of 64 CSR entries into its lanes, then
// broadcasts entry j via __shfl (register) -> h-gather addresses are available
// immediately, loads pipeline instead of serializing on the csr->h L2 chain.
__global__ __launch_bounds__(256) void k_agg_enc(
    const float* __restrict__ h, const int2* __restrict__ csr,
    const int* __restrict__ base, const int* __restrict__ cnt,
    const float* __restrict__ dinv, const float* __restrict__ b_enc,
    __hip_bfloat16* __restrict__ enc)
{
    int i = blockIdx.x * 2 + (threadIdx.x >> 7);
    int ch = threadIdx.x & 127;
    if (i >= N_NODES) {                      // pad rows for the MFMA decoder
        enc[(size_t)i * HID + ch] = __float2bfloat16(0.0f);
        return;
    }
    int lane = threadIdx.x & 63;
    float di = dinv[i];
    float a0 = di * di * h[(size_t)i * HID + ch];
    float a1 = 0.0f, a2 = 0.0f, a3 = 0.0f;
    int j0 = base[i], d = cnt[i];
    for (int b = 0; b < d; b += 64) {
        int cw = d - b;
        if (cw > 64) cw = 64;
        int2 p = make_int2(0, 0);
        if (lane < cw) p = csr[j0 + b + lane];
        int px = p.x, py = p.y;
        int j = 0;
        for (; j + 4 <= cw; j += 4) {
            int s0 = __shfl(px, j),     s1 = __shfl(px, j + 1);
            int s2 = __shfl(px, j + 2), s3 = __shfl(px, j + 3);
            float w0 = __int_as_float(__shfl(py, j));
            float w1 = __int_as_float(__shfl(py, j + 1));
            float w2 = __int_as_float(__shfl(py, j + 2));
            float w3 = __int_as_float(__shfl(py, j + 3));
            a0 += w0 * h[(size_t)s0 * HID + ch];
            a1 += w1 * h[(size_t)s1 * HID + ch];
            a2 += w2 * h[(size_t)s2 * HID + ch];
            a3 += w3 * h[(size_t)s3 * HID + ch];
        }
        for (; j < cw; ++j) {
            int s = __shfl(px, j);
            float w = __int_as_float(__shfl(py, j));
            a0 += w * h[(size_t)s * HID + ch];
        }
    }
    enc[(size_t)i * HID + ch] = __float2bfloat16(((a0 + a1) + (a2 + a3)) + b_enc[ch]);
}

// ---------- decoder GEMM + bias + sigmoid, LDS-staged 128x128 tile ----------
// 64 KiB LDS -> 2 blocks/CU: store drain of one block overlaps stage+compute of
// the other; decoder sits at ~the 400 MB / 67 us write floor.
// K = HID = 128 staged in one shot. 4 waves as 2(m)x2(n), wave tile 64x64.
// LDS XOR swizzle (byte ^= (row&7)<<4) on BOTH global source (linear LDS dest)
// and ds_read addresses. Operand-swapped MFMA (acc = mfma(b, a, acc)):
//   value = C[m = mbase+mi*16+l16][n = nbase+ni*16+quad*4+r] -> aligned f32x4 stores.
__global__ __launch_bounds__(256) void k_dec_gemm(
    const __hip_bfloat16* __restrict__ A, const __hip_bfloat16* __restrict__ BT,
    const float* __restrict__ bias, float* __restrict__ C)
{
    extern __shared__ char lds[];
    char* ldsA = lds;             // 32768 B (128 rows x 256 B)
    char* ldsB = lds + 32768;     // 32768 B

    const int NT = 80;            // 80x80 = 6400 blocks, %8==0 -> bijective swizzle
    int orig = blockIdx.x;
    int wg = (orig & 7) * 800 + (orig >> 3);
    int bx = wg % NT, by = wg / NT;   // consecutive wg in an XCD share by -> A panel L2-hot

    int tid = threadIdx.x;
    int wv = tid >> 6, lane = tid & 63;
    int l16 = lane & 15, quad = lane >> 4;
    int wm = wv >> 1, wn = wv & 1;

    // ---- stage both tiles (each wave: 8 x 1KB for A, 8 x 1KB for B) ----
    {
        const char* gA = (const char*)A + (size_t)by * 32768;
        const char* gB = (const char*)BT + (size_t)bx * 32768;
        int wb = wv * 1024;
#pragma unroll
        for (int it = 0; it < 8; ++it) {
            int L = wb + it * 4096 + lane * 16;     // linear LDS byte this lane fills
            int row = L >> 8;
            int src = (row << 8) | ((L & 255) ^ ((row & 7) << 4));  // inverse-swizzled source
            gload_lds16(gA + src, ldsA + wb + it * 4096);
        }
#pragma unroll
        for (int it = 0; it < 8; ++it) {
            int L = wb + it * 4096 + lane * 16;
            int row = L >> 8;
            int src = (row << 8) | ((L & 255) ^ ((row & 7) << 4));
            gload_lds16(gB + src, ldsB + wb + it * 4096);
        }
    }
    asm volatile("s_waitcnt vmcnt(0)" ::: "memory");
    __syncthreads();

    // ---- compute: 4 K-steps x (4 b-frags + 4 a-frags) x 16 MFMA ----
    f32x4 acc[4][4] = {};
    int qb = quad * 16;
#pragma unroll
    for (int ks = 0; ks < 4; ++ks) {
        int kb = ks * 64 + qb;      // byte col of this lane's 16B fragment (pre-swizzle)
        bf16x8 a[4], b[4];
#pragma unroll
        for (int ni = 0; ni < 4; ++ni) {
            int r = wn * 64 + ni * 16 + l16;
            b[ni] = *(const bf16x8*)(ldsB + ((r << 8) + (kb ^ ((r & 7) << 4))));
        }
#pragma unroll
        for (int mi = 0; mi < 4; ++mi) {
            int r = wm * 64 + mi * 16 + l16;
            a[mi] = *(const bf16x8*)(ldsA + ((r << 8) + (kb ^ ((r & 7) << 4))));
        }
#pragma unroll
        for (int mi = 0; mi < 4; ++mi)
#pragma unroll
            for (int ni = 0; ni < 4; ++ni)
                acc[mi][ni] = __builtin_amdgcn_mfma_f32_16x16x32_bf16(b[ni], a[mi], acc[mi][ni], 0, 0, 0);
    }

    // ---- epilogue: bias (hoisted) + sigmoid + aligned f32x4 stores ----
    int m_w = by * 128 + wm * 64;
    int n_w = bx * 128 + wn * 64;
    f32x4 bv[4];
#pragma unroll
    for (int ni = 0; ni < 4; ++ni) {
        int n4 = n_w + ni * 16 + quad * 4;
        bv[ni] = (n4 < N_NODES) ? *(const f32x4*)(bias + n4) : f32x4{};
    }
#pragma unroll
    for (int mi = 0; mi < 4; ++mi) {
        int m = m_w + mi * 16 + l16;
        if (m >= N_NODES) continue;
        size_t rowoff = (size_t)m * N_NODES;
#pragma unroll
        for (int ni = 0; ni < 4; ++ni) {
            int n4 = n_w + ni * 16 + quad * 4;
            if (n4 >= N_NODES) continue;
            f32x4 z = acc[mi][ni];
            f32x4 s;
#pragma unroll
            for (int r = 0; r < 4; ++r) {
                float e = __expf(-(z[r] + bv[ni][r]));
                s[r] = __builtin_amdgcn_rcpf(1.0f + e);
            }
            *(f32x4*)(C + rowoff + n4) = s;
        }
    }
}

extern "C" void kernel_launch(void* const* d_in, const int* in_sizes, int n_in,
                              void* d_out, int out_size, void* d_ws, size_t ws_size,
                              hipStream_t stream) {
    const float* x     = (const float*)d_in[0];
    const int*   ei    = (const int*)d_in[1];
    const float* W_enc = (const float*)d_in[2];
    const float* b_enc = (const float*)d_in[3];
    const float* W_dec = (const float*)d_in[4];
    const float* b_dec = (const float*)d_in[5];
    float* out = (float*)d_out;
    const int E = in_sizes[1] / 2;

    // carve workspace
    char* p = (char*)d_ws;
    auto carve = [&](size_t bytes) -> char* {
        char* r = p;
        p += (bytes + 255) & ~(size_t)255;
        return r;
    };
    int*   cnt    = (int*)carve((size_t)NPAD * 4);
    int*   base   = (int*)carve((size_t)NPAD * 4);
    int*   cursor = (int*)carve((size_t)NPAD * 4);
    float* dinv   = (float*)carve((size_t)NPAD * 4);
    int2*  csr    = (int2*)carve((size_t)E * 8);
    float* h      = (float*)carve((size_t)N_NODES * HID * 4);
    __hip_bfloat16* wencT = (__hip_bfloat16*)carve((size_t)HID * IN_DIM * 2);
    __hip_bfloat16* encb  = (__hip_bfloat16*)carve((size_t)NPAD * HID * 2);
    __hip_bfloat16* wdecT = (__hip_bfloat16*)carve((size_t)NPAD * HID * 2);

    // head: zero cnt + W_enc cast in one launch
    k_prep<<<dim3(40 + HID * IN_DIM / 256), dim3(256), 0, stream>>>(W_enc, wencT, cnt);
    // CSR build (counting sort by dst) + dinv
    k_hist<<<dim3((E + 255) / 256), dim3(256), 0, stream>>>(ei, cnt, E);
    k_scan<<<dim3(1), dim3(1024), 0, stream>>>(cnt, base, cursor, dinv);
    k_fill<<<dim3((E + 255) / 256), dim3(256), 0, stream>>>(ei, dinv, cursor, csr, E);

    // W_dec transpose+cast (independent of CSR chain)
    k_wdec_t<<<dim3(NPAD / 32, HID / 32), dim3(32, 8), 0, stream>>>(W_dec, wdecT);

    // encoder GEMM in bf16 (fused f32->bf16 load of x)
    k_enc_gemm<<<dim3((N_NODES + 31) / 32), dim3(256), 0, stream>>>(x, wencT, h);

    // fused aggregate + bias + bf16 cast (shfl-broadcast CSR, pipelined gather)
    k_agg_enc<<<dim3(NPAD / 2), dim3(256), 0, stream>>>(h, csr, base, cnt, dinv, b_enc, encb);

    // decoder GEMM + bias + sigmoid: LDS-staged 128x128 tiles, 64 KiB LDS, 2 blocks/CU
    k_dec_gemm<<<dim3(80 * 80), dim3(256), 65536, stream>>>(encb, wdecT, b_dec, out);
}